// Round 2
// baseline (2660.785 us; speedup 1.0000x reference)
//
#include <hip/hip_runtime.h>
#include <stdint.h>

#define N_ATOM 100000
#define M_NBR 12
#define A_FEA 128
#define E_FEA 64
#define KDIM 320
#define GDIM 256
#define ROWS (N_ATOM*M_NBR)
#define BM 96
#define NTILES (ROWS/BM)      // 12500
#define GRID_P 2500           // 5 tiles per block
#define TPB 256
#define APAD 328              // LDS row stride (ushort) for A tile
#define ACTPAD 132            // LDS row stride (f32) for act tile
#define BN_EPS 1e-5f

typedef unsigned short u16;
typedef unsigned int u32;
typedef __attribute__((ext_vector_type(8))) short short8;
typedef __attribute__((ext_vector_type(4))) float f32x4;

// ---- workspace layout ----
#define WF_ELEMS (KDIM*GDIM)                    // 81920 bf16
#define WSF_BYTE_OFF (WF_ELEMS*2)               // 163840
#define WSF_ELEMS (A_FEA*A_FEA)                 // 16384 bf16
#define STATS_BYTE_OFF (WSF_BYTE_OFF + WSF_ELEMS*2)   // 196608
#define S_BN1SUM 0
#define S_BN1SSQ 256
#define S_S1 512
#define S_T1 768
#define S_BN2SUM 1024
#define S_BN2SSQ 1152
#define S_S2 1280
#define S_T2 1408
#define STATS_F32 1536

__device__ __forceinline__ u16 f2bf(float x) {
    union { float f; u32 u; } v; v.f = x;
    u32 r = v.u + 0x7FFFu + ((v.u >> 16) & 1u);
    return (u16)(r >> 16);
}

__device__ __forceinline__ float softplus_f(float x) {
    return fmaxf(x, 0.f) + __logf(1.f + __expf(-fabsf(x)));
}
__device__ __forceinline__ float sigmoid_f(float x) {
    return 1.f / (1.f + __expf(-x));
}

// Zero the bn accumulator slots. A plain kernel (NOT hipMemsetAsync) so it is
// guaranteed to be a replayed graph node -> every replay starts from zero.
__global__ void zero_stats(float* __restrict__ stats) {
    int t = threadIdx.x;              // 256
    stats[t] = 0.f;                   // BN1SUM [0,256) + BN1SSQ [256,512)
    stats[256 + t] = 0.f;
    stats[1024 + t] = 0.f;            // BN2SUM [1024,1152) + BN2SSQ [1152,1280)
}

// Pack W_full and W_skip into MFMA B-fragment order (bf16).
// wf frag idx = (kt*16+ct)*64 + l, elem i -> W[kt*32 + (l>>4)*8 + i][ct*16 + (l&15)]
__global__ void prep_pack(const float* __restrict__ Wfull,
                          const float* __restrict__ Wskip,
                          u16* __restrict__ wf, u16* __restrict__ wsf) {
    int tid = blockIdx.x * blockDim.x + threadIdx.x;
    if (tid < 10240) {
        int l = tid & 63;
        int ct = (tid >> 6) & 15;
        int kt = tid >> 10;
        int fr = l & 15, fq = l >> 4;
        int col = ct * 16 + fr;
        int k0 = kt * 32 + fq * 8;
        u16 tmp[8];
        #pragma unroll
        for (int i = 0; i < 8; ++i) tmp[i] = f2bf(Wfull[(k0 + i) * GDIM + col]);
        uint4 pk;
        pk.x = (u32)tmp[0] | ((u32)tmp[1] << 16);
        pk.y = (u32)tmp[2] | ((u32)tmp[3] << 16);
        pk.z = (u32)tmp[4] | ((u32)tmp[5] << 16);
        pk.w = (u32)tmp[6] | ((u32)tmp[7] << 16);
        *reinterpret_cast<uint4*>(&wf[tid * 8]) = pk;
    } else if (tid < 12288) {
        int t2 = tid - 10240;
        int l = t2 & 63;
        int ct = (t2 >> 6) & 7;
        int kt = t2 >> 9;
        int fr = l & 15, fq = l >> 4;
        int col = ct * 16 + fr;
        int k0 = kt * 32 + fq * 8;
        u16 tmp[8];
        #pragma unroll
        for (int i = 0; i < 8; ++i) tmp[i] = f2bf(Wskip[(k0 + i) * A_FEA + col]);
        uint4 pk;
        pk.x = (u32)tmp[0] | ((u32)tmp[1] << 16);
        pk.y = (u32)tmp[2] | ((u32)tmp[3] << 16);
        pk.z = (u32)tmp[4] | ((u32)tmp[5] << 16);
        pk.w = (u32)tmp[6] | ((u32)tmp[7] << 16);
        *reinterpret_cast<uint4*>(&wsf[t2 * 8]) = pk;
    }
}

// PASS 1: GEMM -> accumulate per-column sum & sumsq of raw gated
// PASS 2: GEMM -> affine (s1,t1) -> sigmoid*softplus -> sum over m -> d_out;
//         accumulate bn2 stats
template<int PASS>
__launch_bounds__(TPB, 2)
__global__ void pass_kernel(const float* __restrict__ atom_in,
                            const float* __restrict__ nbr_fea,
                            const int* __restrict__ nbr_idx,
                            const u16* __restrict__ wf,
                            float* __restrict__ stats,
                            float* __restrict__ out_ns) {
    __shared__ union {
        u16 a[BM * APAD];          // 62976 B
        float act[BM * ACTPAD];    // 50688 B
    } sh;

    const int t = threadIdx.x;
    const int w = t >> 6, l = t & 63, fr = l & 15, fq = l >> 4;
    const int ct0 = 2 * w;

    int colp[4];
    colp[0] = ct0 * 16 + fr;
    colp[1] = colp[0] + 16;
    colp[2] = colp[0] + 128;
    colp[3] = colp[1] + 128;

    float s1v[4], t1v[4];
    if (PASS == 2) {
        #pragma unroll
        for (int p = 0; p < 4; ++p) {
            s1v[p] = stats[S_S1 + colp[p]];
            t1v[p] = stats[S_T1 + colp[p]];
        }
    }
    float ls[4] = {0.f,0.f,0.f,0.f}, lq[4] = {0.f,0.f,0.f,0.f};
    float bsum = 0.f, bssq = 0.f;

    for (int tile = blockIdx.x; tile < NTILES; tile += GRID_P) {
        const int n0 = tile * 8;

        __syncthreads();   // protect LDS from previous iteration readers
        // ---- stage A tile: 96 rows x 320 cols bf16 ----
        for (int it = 0; it < 15; ++it) {
            int c = t + it * TPB;            // 0..3839
            int row = c / 40;
            int seg = c - row * 40;
            int an = row / 12;
            int m  = row - an * 12;
            int na = n0 + an;
            const float* src;
            if (seg < 16) {
                src = atom_in + (size_t)na * A_FEA + seg * 8;
            } else if (seg < 32) {
                int j = nbr_idx[na * M_NBR + m];
                src = atom_in + (size_t)j * A_FEA + (seg - 16) * 8;
            } else {
                src = nbr_fea + ((size_t)na * M_NBR + m) * E_FEA + (seg - 32) * 8;
            }
            float4 x0 = *reinterpret_cast<const float4*>(src);
            float4 x1 = *reinterpret_cast<const float4*>(src + 4);
            uint4 pk;
            pk.x = (u32)f2bf(x0.x) | ((u32)f2bf(x0.y) << 16);
            pk.y = (u32)f2bf(x0.z) | ((u32)f2bf(x0.w) << 16);
            pk.z = (u32)f2bf(x1.x) | ((u32)f2bf(x1.y) << 16);
            pk.w = (u32)f2bf(x1.z) | ((u32)f2bf(x1.w) << 16);
            *reinterpret_cast<uint4*>(&sh.a[row * APAD + seg * 8]) = pk;
        }
        __syncthreads();

        // ---- MFMA: 6 row-tiles x 4 col-tiles, K = 10 x 32 ----
        f32x4 acc[6][4];
        #pragma unroll
        for (int rt = 0; rt < 6; ++rt)
            #pragma unroll
            for (int p = 0; p < 4; ++p)
                acc[rt][p] = (f32x4){0.f,0.f,0.f,0.f};

        for (int kt = 0; kt < 10; ++kt) {
            short8 af[6], bf[4];
            #pragma unroll
            for (int rt = 0; rt < 6; ++rt)
                af[rt] = *reinterpret_cast<const short8*>(
                    &sh.a[(rt * 16 + fr) * APAD + kt * 32 + fq * 8]);
            #pragma unroll
            for (int p = 0; p < 4; ++p) {
                int ct = (p < 2) ? (ct0 + p) : (ct0 + 8 + (p - 2));
                bf[p] = *reinterpret_cast<const short8*>(
                    &wf[((kt * 16 + ct) * 64 + l) * 8]);
            }
            #pragma unroll
            for (int rt = 0; rt < 6; ++rt)
                #pragma unroll
                for (int p = 0; p < 4; ++p)
                    acc[rt][p] = __builtin_amdgcn_mfma_f32_16x16x32_bf16(
                        af[rt], bf[p], acc[rt][p], 0, 0, 0);
        }

        if (PASS == 1) {
            #pragma unroll
            for (int p = 0; p < 4; ++p)
                #pragma unroll
                for (int rt = 0; rt < 6; ++rt)
                    #pragma unroll
                    for (int j = 0; j < 4; ++j) {
                        float v = acc[rt][p][j];
                        ls[p] += v;
                        lq[p] = fmaf(v, v, lq[p]);
                    }
        } else {
            __syncthreads();  // all waves done reading sh.a
            #pragma unroll
            for (int rt = 0; rt < 6; ++rt)
                #pragma unroll
                for (int p = 0; p < 2; ++p)
                    #pragma unroll
                    for (int j = 0; j < 4; ++j) {
                        float gf = fmaf(acc[rt][p][j],     s1v[p],     t1v[p]);
                        float gc = fmaf(acc[rt][2 + p][j], s1v[2 + p], t1v[2 + p]);
                        float a = sigmoid_f(gf) * softplus_f(gc);
                        int row = rt * 16 + fq * 4 + j;
                        int colact = ct0 * 16 + p * 16 + fr;
                        sh.act[row * ACTPAD + colact] = a;
                    }
            __syncthreads();
            // reduce over m=12, write nbr_sumed to d_out, accumulate bn2 stats
            #pragma unroll
            for (int i = 0; i < 4; ++i) {
                int o = i * TPB + t;
                int a = o >> 7;            // atom 0..7
                int c = o & 127;           // col (== t&127, constant per thread)
                float S = 0.f;
                #pragma unroll
                for (int mm = 0; mm < 12; ++mm)
                    S += sh.act[(a * 12 + mm) * ACTPAD + c];
                out_ns[(size_t)(n0 + a) * A_FEA + c] = S;
                bsum += S;
                bssq = fmaf(S, S, bssq);
            }
        }
    }

    if (PASS == 1) {
        #pragma unroll
        for (int p = 0; p < 4; ++p) {
            float s = ls[p], q = lq[p];
            s += __shfl_xor(s, 16, 64);
            s += __shfl_xor(s, 32, 64);
            q += __shfl_xor(q, 16, 64);
            q += __shfl_xor(q, 32, 64);
            if (fq == 0) {
                atomicAdd(&stats[S_BN1SUM + colp[p]], s);
                atomicAdd(&stats[S_BN1SSQ + colp[p]], q);
            }
        }
    } else {
        __syncthreads();
        if (t >= 128) {
            sh.act[(t - 128) * 2]     = bsum;
            sh.act[(t - 128) * 2 + 1] = bssq;
        }
        __syncthreads();
        if (t < 128) {
            bsum += sh.act[t * 2];
            bssq += sh.act[t * 2 + 1];
            atomicAdd(&stats[S_BN2SUM + t], bsum);
            atomicAdd(&stats[S_BN2SSQ + t], bssq);
        }
    }
}

__global__ void finalize1(const float* __restrict__ g1, const float* __restrict__ b1,
                          float* __restrict__ stats) {
    int c = threadIdx.x;  // 256
    const float inv_cnt = 1.f / (float)ROWS;
    float mean = stats[S_BN1SUM + c] * inv_cnt;
    float var  = stats[S_BN1SSQ + c] * inv_cnt - mean * mean;
    float iv = rsqrtf(var + BN_EPS);
    float s = g1[c] * iv;
    stats[S_S1 + c] = s;
    stats[S_T1 + c] = fmaf(-mean, s, b1[c]);
}

__global__ void finalize2(const float* __restrict__ g2, const float* __restrict__ b2,
                          float* __restrict__ stats) {
    int c = threadIdx.x;  // 128
    const float inv_cnt = 1.f / (float)N_ATOM;
    float mean = stats[S_BN2SUM + c] * inv_cnt;
    float var  = stats[S_BN2SSQ + c] * inv_cnt - mean * mean;
    float iv = rsqrtf(var + BN_EPS);
    float s = g2[c] * iv;
    stats[S_S2 + c] = s;
    stats[S_T2 + c] = fmaf(-mean, s, b2[c]);
}

// out[n][c] = softplus( (atom_in @ W_skip)[n][c] + b_skip[c] + S*s2[c] + t2[c] )
// S = d_out[n][c] (nbr_sumed), overwritten in place.
#define BM5 64
__launch_bounds__(256, 2)
__global__ void skip_kernel(const float* __restrict__ atom_in,
                            const u16* __restrict__ wsf,
                            const float* __restrict__ b_skip,
                            const float* __restrict__ stats,
                            float* __restrict__ out) {
    __shared__ u16 a5[BM5 * 136];
    const int t = threadIdx.x;
    const int w = t >> 6, l = t & 63, fr = l & 15, fq = l >> 4;
    const int n0 = blockIdx.x * BM5;

    for (int it = 0; it < 4; ++it) {
        int c = t + it * 256;     // 0..1023
        int row = c >> 4;
        int seg = c & 15;
        int n = n0 + row;
        uint4 pk = {0u, 0u, 0u, 0u};
        if (n < N_ATOM) {
            const float* src = atom_in + (size_t)n * A_FEA + seg * 8;
            float4 x0 = *reinterpret_cast<const float4*>(src);
            float4 x1 = *reinterpret_cast<const float4*>(src + 4);
            pk.x = (u32)f2bf(x0.x) | ((u32)f2bf(x0.y) << 16);
            pk.y = (u32)f2bf(x0.z) | ((u32)f2bf(x0.w) << 16);
            pk.z = (u32)f2bf(x1.x) | ((u32)f2bf(x1.y) << 16);
            pk.w = (u32)f2bf(x1.z) | ((u32)f2bf(x1.w) << 16);
        }
        *reinterpret_cast<uint4*>(&a5[row * 136 + seg * 8]) = pk;
    }
    __syncthreads();

    f32x4 acc[4][2];
    #pragma unroll
    for (int rt = 0; rt < 4; ++rt)
        #pragma unroll
        for (int p = 0; p < 2; ++p)
            acc[rt][p] = (f32x4){0.f,0.f,0.f,0.f};

    for (int kt = 0; kt < 4; ++kt) {
        short8 af[4], bf[2];
        #pragma unroll
        for (int rt = 0; rt < 4; ++rt)
            af[rt] = *reinterpret_cast<const short8*>(
                &a5[(rt * 16 + fr) * 136 + kt * 32 + fq * 8]);
        #pragma unroll
        for (int p = 0; p < 2; ++p) {
            int ct = 2 * w + p;
            bf[p] = *reinterpret_cast<const short8*>(
                &wsf[((kt * 8 + ct) * 64 + l) * 8]);
        }
        #pragma unroll
        for (int rt = 0; rt < 4; ++rt)
            #pragma unroll
            for (int p = 0; p < 2; ++p)
                acc[rt][p] = __builtin_amdgcn_mfma_f32_16x16x32_bf16(
                    af[rt], bf[p], acc[rt][p], 0, 0, 0);
    }

    #pragma unroll
    for (int p = 0; p < 2; ++p) {
        int col = w * 32 + p * 16 + fr;
        float bs = b_skip[col];
        float s2 = stats[S_S2 + col];
        float t2 = stats[S_T2 + col];
        #pragma unroll
        for (int rt = 0; rt < 4; ++rt)
            #pragma unroll
            for (int j = 0; j < 4; ++j) {
                int n = n0 + rt * 16 + fq * 4 + j;
                if (n < N_ATOM) {
                    size_t o = (size_t)n * A_FEA + col;
                    float S = out[o];
                    float v = acc[rt][p][j] + bs + fmaf(S, s2, t2);
                    out[o] = softplus_f(v);
                }
            }
    }
}

extern "C" void kernel_launch(void* const* d_in, const int* in_sizes, int n_in,
                              void* d_out, int out_size, void* d_ws, size_t ws_size,
                              hipStream_t stream) {
    (void)in_sizes; (void)n_in; (void)out_size; (void)ws_size;
    const float* atom_in = (const float*)d_in[0];
    const float* nbr_fea = (const float*)d_in[1];
    const int*   nbr_idx = (const int*)d_in[2];
    const float* Wfull   = (const float*)d_in[3];
    // d_in[4] = b_full: cancels exactly under batchnorm1 -> unused
    const float* g1      = (const float*)d_in[5];
    const float* b1      = (const float*)d_in[6];
    const float* g2      = (const float*)d_in[7];
    const float* b2      = (const float*)d_in[8];
    const float* Wsk     = (const float*)d_in[9];
    const float* bsk     = (const float*)d_in[10];
    float* out = (float*)d_out;

    u16* wf    = (u16*)d_ws;
    u16* wsf   = (u16*)((char*)d_ws + WSF_BYTE_OFF);
    float* stats = (float*)((char*)d_ws + STATS_BYTE_OFF);

    zero_stats<<<1, 256, 0, stream>>>(stats);
    prep_pack<<<48, 256, 0, stream>>>(Wfull, Wsk, wf, wsf);
    pass_kernel<1><<<GRID_P, TPB, 0, stream>>>(atom_in, nbr_fea, nbr_idx, wf, stats, out);
    finalize1<<<1, 256, 0, stream>>>(g1, b1, stats);
    pass_kernel<2><<<GRID_P, TPB, 0, stream>>>(atom_in, nbr_fea, nbr_idx, wf, stats, out);
    finalize2<<<1, 128, 0, stream>>>(g2, b2, stats);
    skip_kernel<<<(N_ATOM + BM5 - 1) / BM5, 256, 0, stream>>>(atom_in, wsf, bsk, stats, out);
}

// Round 3
// 812.799 us; speedup vs baseline: 3.2736x; 3.2736x over previous
//
#include <hip/hip_runtime.h>
#include <stdint.h>

#define N_ATOM 100000
#define M_NBR 12
#define A_FEA 128
#define E_FEA 64
#define KDIM 320
#define GDIM 256
#define ROWS (N_ATOM*M_NBR)
#define BN_EPS 1e-5f

typedef unsigned short u16;
typedef unsigned int u32;
typedef __attribute__((ext_vector_type(8))) short short8;
typedef __attribute__((ext_vector_type(4))) float f32x4;

// ---- stats slot indices (floats) ----
#define S_BN1SUM 0
#define S_BN1SSQ 256
#define S_S1 512
#define S_T1 768
#define S_BN2SUM 1024
#define S_BN2SSQ 1152
#define S_S2 1280
#define S_T2 1408
#define STATS_F32 1536

// ---- workspace layout (shared base for all paths) ----
// [0,163840): packed weights (slow: wf 320x256 | fast: wpq 128KB + w3 32KB)
// [163840,196608): packed skip weights (both paths)
// [196608,202752): stats (1536 f32)
// fast/mid extras:
#define WPQ_OFF 0
#define W3_OFF 131072
#define WSK_OFF 163840
#define STATS_OFF 196608
#define P_OFF 202752
#define PQ_BYTES ((size_t)N_ATOM*256*2)            // 51,200,000
#define Q_OFF (P_OFF + PQ_BYTES)
#define GATED_OFF (Q_OFF + PQ_BYTES)               // 102,602,752
#define GATED_BYTES ((size_t)ROWS*256*2)           // 614,400,000

__device__ __forceinline__ u16 f2bf(float x) {
    union { float f; u32 u; } v; v.f = x;
    u32 r = v.u + 0x7FFFu + ((v.u >> 16) & 1u);
    return (u16)(r >> 16);
}
__device__ __forceinline__ float bf2f(u16 u) {
    union { u32 u; float f; } v; v.u = ((u32)u) << 16;
    return v.f;
}
__device__ __forceinline__ float softplus_f(float x) {
    return fmaxf(x, 0.f) + __logf(1.f + __expf(-fabsf(x)));
}
__device__ __forceinline__ float sigmoid_f(float x) {
    return 1.f / (1.f + __expf(-x));
}

// Zero bn accumulators every launch (plain kernel -> always a graph node).
__global__ void zero_stats(float* __restrict__ stats) {
    int t = threadIdx.x;              // 256
    stats[t] = 0.f;
    stats[256 + t] = 0.f;
    stats[1024 + t] = 0.f;
}

__global__ void finalize1(const float* __restrict__ g1, const float* __restrict__ b1,
                          float* __restrict__ stats) {
    int c = threadIdx.x;  // 256
    const float inv_cnt = 1.f / (float)ROWS;
    float mean = stats[S_BN1SUM + c] * inv_cnt;
    float var  = stats[S_BN1SSQ + c] * inv_cnt - mean * mean;
    float iv = rsqrtf(var + BN_EPS);
    float s = g1[c] * iv;
    stats[S_S1 + c] = s;
    stats[S_T1 + c] = fmaf(-mean, s, b1[c]);
}

__global__ void finalize2(const float* __restrict__ g2, const float* __restrict__ b2,
                          float* __restrict__ stats) {
    int c = threadIdx.x;  // 128
    const float inv_cnt = 1.f / (float)N_ATOM;
    float mean = stats[S_BN2SUM + c] * inv_cnt;
    float var  = stats[S_BN2SSQ + c] * inv_cnt - mean * mean;
    float iv = rsqrtf(var + BN_EPS);
    float s = g2[c] * iv;
    stats[S_S2 + c] = s;
    stats[S_T2 + c] = fmaf(-mean, s, b2[c]);
}

// =====================================================================
// FAST/MID path kernels
// =====================================================================

// Pack Wpq (B for the P/Q GEMM: 128K x 512 cols), W3 (64 x 256), Wsk (128 x 128)
// into MFMA B-fragment order.
__global__ void prep_pack_fast(const float* __restrict__ Wfull,
                               const float* __restrict__ Wskip,
                               u16* __restrict__ wpq, u16* __restrict__ w3,
                               u16* __restrict__ wsk) {
    int tid = blockIdx.x * blockDim.x + threadIdx.x;
    int l = tid & 63, fr = l & 15, fq = l >> 4;
    if (tid < 8192) {
        int ct = (tid >> 6) & 31;
        int kt = tid >> 11;                 // 0..3
        int c = ct * 16 + fr;               // 0..511
        int k0 = kt * 32 + fq * 8;          // 0..127
        u16 tmp[8];
        #pragma unroll
        for (int i = 0; i < 8; ++i) {
            int kk = k0 + i;
            float v = (c < 256) ? Wfull[kk * GDIM + c]
                                : Wfull[(128 + kk) * GDIM + (c - 256)];
            tmp[i] = f2bf(v);
        }
        uint4 pk;
        pk.x = (u32)tmp[0] | ((u32)tmp[1] << 16);
        pk.y = (u32)tmp[2] | ((u32)tmp[3] << 16);
        pk.z = (u32)tmp[4] | ((u32)tmp[5] << 16);
        pk.w = (u32)tmp[6] | ((u32)tmp[7] << 16);
        *reinterpret_cast<uint4*>(&wpq[tid * 8]) = pk;
    } else if (tid < 10240) {
        int t2 = tid - 8192;
        int ct = (t2 >> 6) & 15;
        int kt = t2 >> 10;                  // 0..1
        int c = ct * 16 + fr;
        int k0 = kt * 32 + fq * 8;          // 0..63
        u16 tmp[8];
        #pragma unroll
        for (int i = 0; i < 8; ++i) tmp[i] = f2bf(Wfull[(256 + k0 + i) * GDIM + c]);
        uint4 pk;
        pk.x = (u32)tmp[0] | ((u32)tmp[1] << 16);
        pk.y = (u32)tmp[2] | ((u32)tmp[3] << 16);
        pk.z = (u32)tmp[4] | ((u32)tmp[5] << 16);
        pk.w = (u32)tmp[6] | ((u32)tmp[7] << 16);
        *reinterpret_cast<uint4*>(&w3[t2 * 8]) = pk;
    } else if (tid < 12288) {
        int t3 = tid - 10240;
        int ct = (t3 >> 6) & 7;
        int kt = t3 >> 9;                   // 0..3
        int c = ct * 16 + fr;
        int k0 = kt * 32 + fq * 8;
        u16 tmp[8];
        #pragma unroll
        for (int i = 0; i < 8; ++i) tmp[i] = f2bf(Wskip[(k0 + i) * A_FEA + c]);
        uint4 pk;
        pk.x = (u32)tmp[0] | ((u32)tmp[1] << 16);
        pk.y = (u32)tmp[2] | ((u32)tmp[3] << 16);
        pk.z = (u32)tmp[4] | ((u32)tmp[5] << 16);
        pk.w = (u32)tmp[6] | ((u32)tmp[7] << 16);
        *reinterpret_cast<uint4*>(&wsk[t3 * 8]) = pk;
    }
}

// P[n] = atom_in[n] @ Wfull[0:128];  Q[n] = atom_in[n] @ Wfull[128:256]
// Single GEMM: A (100000x128) @ B (128x512), output bf16.
__launch_bounds__(256)
__global__ void pq_kernel(const float* __restrict__ atom_in,
                          const u16* __restrict__ wpq,
                          u16* __restrict__ Pb, u16* __restrict__ Qb) {
    __shared__ u16 al[64 * 130];
    const int t = threadIdx.x;
    const int w = t >> 6, l = t & 63, fr = l & 15, fq = l >> 4;
    const int n0 = blockIdx.x * 64;

    #pragma unroll
    for (int it = 0; it < 4; ++it) {
        int c = t + it * 256;         // 0..1023
        int row = c >> 4, seg = c & 15;
        int n = n0 + row;
        uint4 pk = {0u, 0u, 0u, 0u};
        if (n < N_ATOM) {
            const float* src = atom_in + (size_t)n * A_FEA + seg * 8;
            float4 x0 = *reinterpret_cast<const float4*>(src);
            float4 x1 = *reinterpret_cast<const float4*>(src + 4);
            pk.x = (u32)f2bf(x0.x) | ((u32)f2bf(x0.y) << 16);
            pk.y = (u32)f2bf(x0.z) | ((u32)f2bf(x0.w) << 16);
            pk.z = (u32)f2bf(x1.x) | ((u32)f2bf(x1.y) << 16);
            pk.w = (u32)f2bf(x1.z) | ((u32)f2bf(x1.w) << 16);
        }
        *reinterpret_cast<uint4*>(&al[row * 130 + seg * 8]) = pk;
    }
    __syncthreads();

    f32x4 acc[4][8];
    #pragma unroll
    for (int rt = 0; rt < 4; ++rt)
        #pragma unroll
        for (int p = 0; p < 8; ++p)
            acc[rt][p] = (f32x4){0.f,0.f,0.f,0.f};

    for (int kt = 0; kt < 4; ++kt) {
        short8 af[4], bf[8];
        #pragma unroll
        for (int rt = 0; rt < 4; ++rt)
            af[rt] = *reinterpret_cast<const short8*>(
                &al[(rt * 16 + fr) * 130 + kt * 32 + fq * 8]);
        #pragma unroll
        for (int p = 0; p < 8; ++p)
            bf[p] = *reinterpret_cast<const short8*>(
                &wpq[((kt * 32 + w * 8 + p) * 64 + l) * 8]);
        #pragma unroll
        for (int rt = 0; rt < 4; ++rt)
            #pragma unroll
            for (int p = 0; p < 8; ++p)
                acc[rt][p] = __builtin_amdgcn_mfma_f32_16x16x32_bf16(
                    af[rt], bf[p], acc[rt][p], 0, 0, 0);
    }

    #pragma unroll
    for (int p = 0; p < 8; ++p) {
        int col = w * 128 + p * 16 + fr;            // 0..511
        u16* dst = (col < 256) ? Pb : Qb;
        int cc = (col < 256) ? col : (col - 256);
        #pragma unroll
        for (int rt = 0; rt < 4; ++rt)
            #pragma unroll
            for (int j = 0; j < 4; ++j) {
                int n = n0 + rt * 16 + fq * 4 + j;
                if (n < N_ATOM) dst[(size_t)n * 256 + cc] = f2bf(acc[rt][p][j]);
            }
    }
}

// Edge-tile kernel. 512 threads (8 waves), tile = 96 rows (8 atoms x 12 nbrs).
// gated = (nbr_fea @ W3) + P[atom] + Q[idx].
// MODE 1: accumulate bn1 sum/ssq; WG=1 additionally writes gated (bf16).
// MODE 2 (mid path): apply bn1 affine + sigmoid*softplus, m-sum -> out; bn2 stats.
#define NTILES_E (ROWS/96)     // 12500
#define GRID_E 2500
template<int MODE, int WG>
__launch_bounds__(512)
__global__ void estage_kernel(const float* __restrict__ nbr_fea,
                              const int* __restrict__ nbr_idx,
                              const u16* __restrict__ w3,
                              const u16* __restrict__ Pb,
                              const u16* __restrict__ Qb,
                              float* __restrict__ stats,
                              u16* __restrict__ gated,
                              float* __restrict__ out_ns) {
    constexpr int SH_BYTES = (MODE == 1) ? (96 * 66 * 2) : (96 * 132 * 4);
    __shared__ __align__(16) unsigned char shraw[SH_BYTES];
    u16* e_lds = (u16*)shraw;
    float* act = (float*)shraw;
    __shared__ int idx_lds[96];

    const int t = threadIdx.x;
    const int w = t >> 6, l = t & 63, fr = l & 15, fq = l >> 4;

    const int col0 = w * 16 + fr;        // filter col 0..127
    const int col1 = 128 + col0;         // core col

    float s1v0, t1v0, s1v1, t1v1;
    if (MODE == 2) {
        s1v0 = stats[S_S1 + col0]; t1v0 = stats[S_T1 + col0];
        s1v1 = stats[S_S1 + col1]; t1v1 = stats[S_T1 + col1];
    }
    float ls0 = 0.f, lq0 = 0.f, ls1 = 0.f, lq1 = 0.f;   // MODE 1
    float bsum = 0.f, bssq = 0.f;                        // MODE 2

    for (int tile = blockIdx.x; tile < NTILES_E; tile += GRID_E) {
        const int r0 = tile * 96;

        __syncthreads();
        for (int c = t; c < 768; c += 512) {
            int row = c >> 3, seg = c & 7;
            const float* src = nbr_fea + (size_t)(r0 + row) * E_FEA + seg * 8;
            float4 x0 = *reinterpret_cast<const float4*>(src);
            float4 x1 = *reinterpret_cast<const float4*>(src + 4);
            uint4 pk;
            pk.x = (u32)f2bf(x0.x) | ((u32)f2bf(x0.y) << 16);
            pk.y = (u32)f2bf(x0.z) | ((u32)f2bf(x0.w) << 16);
            pk.z = (u32)f2bf(x1.x) | ((u32)f2bf(x1.y) << 16);
            pk.w = (u32)f2bf(x1.z) | ((u32)f2bf(x1.w) << 16);
            *reinterpret_cast<uint4*>(&e_lds[row * 66 + seg * 8]) = pk;
        }
        if (t < 96) idx_lds[t] = nbr_idx[r0 + t];
        __syncthreads();

        f32x4 acc[6][2];
        #pragma unroll
        for (int rt = 0; rt < 6; ++rt) {
            acc[rt][0] = (f32x4){0.f,0.f,0.f,0.f};
            acc[rt][1] = (f32x4){0.f,0.f,0.f,0.f};
        }
        #pragma unroll
        for (int kt = 0; kt < 2; ++kt) {
            short8 af[6], bf0, bf1;
            #pragma unroll
            for (int rt = 0; rt < 6; ++rt)
                af[rt] = *reinterpret_cast<const short8*>(
                    &e_lds[(rt * 16 + fr) * 66 + kt * 32 + fq * 8]);
            bf0 = *reinterpret_cast<const short8*>(&w3[((kt * 16 + w) * 64 + l) * 8]);
            bf1 = *reinterpret_cast<const short8*>(&w3[((kt * 16 + 8 + w) * 64 + l) * 8]);
            #pragma unroll
            for (int rt = 0; rt < 6; ++rt) {
                acc[rt][0] = __builtin_amdgcn_mfma_f32_16x16x32_bf16(af[rt], bf0, acc[rt][0], 0, 0, 0);
                acc[rt][1] = __builtin_amdgcn_mfma_f32_16x16x32_bf16(af[rt], bf1, acc[rt][1], 0, 0, 0);
            }
        }

        if (MODE == 2) __syncthreads();   // done reading e_lds; act overlays it

        #pragma unroll
        for (int rt = 0; rt < 6; ++rt) {
            #pragma unroll
            for (int j = 0; j < 4; ++j) {
                int row = rt * 16 + fq * 4 + j;     // 0..95
                int ag = tile * 8 + row / 12;
                int jr = idx_lds[row];
                const u16* prow = Pb + (size_t)ag * 256;
                const u16* qrow = Qb + (size_t)jr * 256;
                float g0 = acc[rt][0][j] + bf2f(prow[col0]) + bf2f(qrow[col0]);
                float g1 = acc[rt][1][j] + bf2f(prow[col1]) + bf2f(qrow[col1]);
                if (MODE == 1) {
                    ls0 += g0; lq0 = fmaf(g0, g0, lq0);
                    ls1 += g1; lq1 = fmaf(g1, g1, lq1);
                    if (WG) {
                        gated[(size_t)(r0 + row) * 256 + col0] = f2bf(g0);
                        gated[(size_t)(r0 + row) * 256 + col1] = f2bf(g1);
                    }
                } else {
                    float gf = fmaf(g0, s1v0, t1v0);
                    float gc = fmaf(g1, s1v1, t1v1);
                    act[row * 132 + col0] = sigmoid_f(gf) * softplus_f(gc);
                }
            }
        }

        if (MODE == 2) {
            __syncthreads();
            #pragma unroll
            for (int i = 0; i < 2; ++i) {
                int o = i * 512 + t;
                int a = o >> 7;            // 0..7
                int c = o & 127;
                float S = 0.f;
                #pragma unroll
                for (int mm = 0; mm < 12; ++mm)
                    S += act[(a * 12 + mm) * 132 + c];
                out_ns[(size_t)(tile * 8 + a) * A_FEA + c] = S;
                bsum += S;
                bssq = fmaf(S, S, bssq);
            }
        }
    }

    if (MODE == 1) {
        float s, q;
        s = ls0 + __shfl_xor(ls0, 16, 64); s += __shfl_xor(s, 32, 64);
        q = lq0 + __shfl_xor(lq0, 16, 64); q += __shfl_xor(q, 32, 64);
        if (fq == 0) {
            atomicAdd(&stats[S_BN1SUM + col0], s);
            atomicAdd(&stats[S_BN1SSQ + col0], q);
        }
        s = ls1 + __shfl_xor(ls1, 16, 64); s += __shfl_xor(s, 32, 64);
        q = lq1 + __shfl_xor(lq1, 16, 64); q += __shfl_xor(q, 32, 64);
        if (fq == 0) {
            atomicAdd(&stats[S_BN1SUM + col1], s);
            atomicAdd(&stats[S_BN1SSQ + col1], q);
        }
    } else {
        __syncthreads();
        if (t >= 128) {
            act[(t - 128) * 2]     = bsum;
            act[(t - 128) * 2 + 1] = bssq;
        }
        __syncthreads();
        if (t < 128) {
            bsum += act[t * 2]       + act[(128 + t) * 2]       + act[(256 + t) * 2];
            bssq += act[t * 2 + 1]   + act[(128 + t) * 2 + 1]   + act[(256 + t) * 2 + 1];
            atomicAdd(&stats[S_BN2SUM + t], bsum);
            atomicAdd(&stats[S_BN2SSQ + t], bssq);
        }
    }
}

// FAST pass 2: stream gated bf16, apply bn1 affine + sigmoid*softplus,
// sum over m -> out (nbr_sumed), accumulate bn2 stats. 64 atoms/block.
__launch_bounds__(256)
__global__ void apply_kernel(const u16* __restrict__ gated,
                             float* __restrict__ stats,
                             float* __restrict__ out) {
    __shared__ float red[4][64][4];
    const int t = threadIdx.x;
    const int lidc = t & 63, aoff = t >> 6;
    const int c0 = lidc * 2;
    const int n0 = blockIdx.x * 64;

    const float s1f0 = stats[S_S1 + c0],     t1f0 = stats[S_T1 + c0];
    const float s1f1 = stats[S_S1 + c0 + 1], t1f1 = stats[S_T1 + c0 + 1];
    const float s1c0 = stats[S_S1 + 128 + c0],     t1c0 = stats[S_T1 + 128 + c0];
    const float s1c1 = stats[S_S1 + 128 + c0 + 1], t1c1 = stats[S_T1 + 128 + c0 + 1];

    float bs0 = 0.f, bq0 = 0.f, bs1 = 0.f, bq1 = 0.f;

    for (int a = aoff; a < 64; a += 4) {
        int n = n0 + a;
        if (n >= N_ATOM) continue;
        float S0 = 0.f, S1 = 0.f;
        const u16* base = gated + (size_t)n * 12 * 256;
        #pragma unroll
        for (int m = 0; m < 12; ++m) {
            u32 uf = *reinterpret_cast<const u32*>(base + m * 256 + c0);
            u32 uc = *reinterpret_cast<const u32*>(base + m * 256 + 128 + c0);
            float f0 = __uint_as_float(uf << 16);
            float f1 = __uint_as_float(uf & 0xFFFF0000u);
            float c_0 = __uint_as_float(uc << 16);
            float c_1 = __uint_as_float(uc & 0xFFFF0000u);
            float gf0 = fmaf(f0, s1f0, t1f0), gf1 = fmaf(f1, s1f1, t1f1);
            float gc0 = fmaf(c_0, s1c0, t1c0), gc1 = fmaf(c_1, s1c1, t1c1);
            S0 += sigmoid_f(gf0) * softplus_f(gc0);
            S1 += sigmoid_f(gf1) * softplus_f(gc1);
        }
        *reinterpret_cast<float2*>(&out[(size_t)n * A_FEA + c0]) = make_float2(S0, S1);
        bs0 += S0; bq0 = fmaf(S0, S0, bq0);
        bs1 += S1; bq1 = fmaf(S1, S1, bq1);
    }

    red[aoff][lidc][0] = bs0; red[aoff][lidc][1] = bq0;
    red[aoff][lidc][2] = bs1; red[aoff][lidc][3] = bq1;
    __syncthreads();
    if (t < 64) {
        float a0 = red[0][t][0] + red[1][t][0] + red[2][t][0] + red[3][t][0];
        float a1 = red[0][t][1] + red[1][t][1] + red[2][t][1] + red[3][t][1];
        float a2 = red[0][t][2] + red[1][t][2] + red[2][t][2] + red[3][t][2];
        float a3 = red[0][t][3] + red[1][t][3] + red[2][t][3] + red[3][t][3];
        atomicAdd(&stats[S_BN2SUM + 2 * t],     a0);
        atomicAdd(&stats[S_BN2SSQ + 2 * t],     a1);
        atomicAdd(&stats[S_BN2SUM + 2 * t + 1], a2);
        atomicAdd(&stats[S_BN2SSQ + 2 * t + 1], a3);
    }
}

// Skip GEMM + bn2 affine + softplus (in place on out). Shared by all paths.
#define BM5 64
__launch_bounds__(256, 2)
__global__ void skip_kernel(const float* __restrict__ atom_in,
                            const u16* __restrict__ wsf,
                            const float* __restrict__ b_skip,
                            const float* __restrict__ stats,
                            float* __restrict__ out) {
    __shared__ u16 a5[BM5 * 136];
    const int t = threadIdx.x;
    const int w = t >> 6, l = t & 63, fr = l & 15, fq = l >> 4;
    const int n0 = blockIdx.x * BM5;

    #pragma unroll
    for (int it = 0; it < 4; ++it) {
        int c = t + it * 256;
        int row = c >> 4, seg = c & 15;
        int n = n0 + row;
        uint4 pk = {0u, 0u, 0u, 0u};
        if (n < N_ATOM) {
            const float* src = atom_in + (size_t)n * A_FEA + seg * 8;
            float4 x0 = *reinterpret_cast<const float4*>(src);
            float4 x1 = *reinterpret_cast<const float4*>(src + 4);
            pk.x = (u32)f2bf(x0.x) | ((u32)f2bf(x0.y) << 16);
            pk.y = (u32)f2bf(x0.z) | ((u32)f2bf(x0.w) << 16);
            pk.z = (u32)f2bf(x1.x) | ((u32)f2bf(x1.y) << 16);
            pk.w = (u32)f2bf(x1.z) | ((u32)f2bf(x1.w) << 16);
        }
        *reinterpret_cast<uint4*>(&a5[row * 136 + seg * 8]) = pk;
    }
    __syncthreads();

    f32x4 acc[4][2];
    #pragma unroll
    for (int rt = 0; rt < 4; ++rt) {
        acc[rt][0] = (f32x4){0.f,0.f,0.f,0.f};
        acc[rt][1] = (f32x4){0.f,0.f,0.f,0.f};
    }
    for (int kt = 0; kt < 4; ++kt) {
        short8 af[4], bf[2];
        #pragma unroll
        for (int rt = 0; rt < 4; ++rt)
            af[rt] = *reinterpret_cast<const short8*>(
                &a5[(rt * 16 + fr) * 136 + kt * 32 + fq * 8]);
        #pragma unroll
        for (int p = 0; p < 2; ++p)
            bf[p] = *reinterpret_cast<const short8*>(
                &wsf[((kt * 8 + 2 * w + p) * 64 + l) * 8]);
        #pragma unroll
        for (int rt = 0; rt < 4; ++rt)
            #pragma unroll
            for (int p = 0; p < 2; ++p)
                acc[rt][p] = __builtin_amdgcn_mfma_f32_16x16x32_bf16(
                    af[rt], bf[p], acc[rt][p], 0, 0, 0);
    }

    #pragma unroll
    for (int p = 0; p < 2; ++p) {
        int col = w * 32 + p * 16 + fr;
        float bs = b_skip[col];
        float s2 = stats[S_S2 + col];
        float t2 = stats[S_T2 + col];
        #pragma unroll
        for (int rt = 0; rt < 4; ++rt)
            #pragma unroll
            for (int j = 0; j < 4; ++j) {
                int n = n0 + rt * 16 + fq * 4 + j;
                if (n < N_ATOM) {
                    size_t o = (size_t)n * A_FEA + col;
                    float S = out[o];
                    out[o] = softplus_f(acc[rt][p][j] + bs + fmaf(S, s2, t2));
                }
            }
    }
}

// =====================================================================
// SLOW fallback path (round-2 validated code, unchanged)
// =====================================================================
#define BM 96
#define NTILES (ROWS/BM)
#define GRID_P 2500
#define TPB 256
#define APAD 328
#define ACTPAD 132

__global__ void prep_pack_slow(const float* __restrict__ Wfull,
                               const float* __restrict__ Wskip,
                               u16* __restrict__ wf, u16* __restrict__ wsf) {
    int tid = blockIdx.x * blockDim.x + threadIdx.x;
    if (tid < 10240) {
        int l = tid & 63;
        int ct = (tid >> 6) & 15;
        int kt = tid >> 10;
        int fr = l & 15, fq = l >> 4;
        int col = ct * 16 + fr;
        int k0 = kt * 32 + fq * 8;
        u16 tmp[8];
        #pragma unroll
        for (int i = 0; i < 8; ++i) tmp[i] = f2bf(Wfull[(k0 + i) * GDIM + col]);
        uint4 pk;
        pk.x = (u32)tmp[0] | ((u32)tmp[1] << 16);
        pk.y = (u32)tmp[2] | ((u32)tmp[3] << 16);
        pk.z = (u32)tmp[4] | ((u32)tmp[5] << 16);
        pk.w = (u32)tmp[6] | ((u32)tmp[7] << 16);
        *reinterpret_cast<uint4*>(&wf[tid * 8]) = pk;
    } else if (tid < 12288) {
        int t2 = tid - 10240;
        int l = t2 & 63;
        int ct = (t2 >> 6) & 7;
        int kt = t2 >> 9;
        int fr = l & 15, fq = l >> 4;
        int col = ct * 16 + fr;
        int k0 = kt * 32 + fq * 8;
        u16 tmp[8];
        #pragma unroll
        for (int i = 0; i < 8; ++i) tmp[i] = f2bf(Wskip[(k0 + i) * A_FEA + col]);
        uint4 pk;
        pk.x = (u32)tmp[0] | ((u32)tmp[1] << 16);
        pk.y = (u32)tmp[2] | ((u32)tmp[3] << 16);
        pk.z = (u32)tmp[4] | ((u32)tmp[5] << 16);
        pk.w = (u32)tmp[6] | ((u32)tmp[7] << 16);
        *reinterpret_cast<uint4*>(&wsf[t2 * 8]) = pk;
    }
}

template<int PASS>
__launch_bounds__(TPB, 2)
__global__ void pass_kernel(const float* __restrict__ atom_in,
                            const float* __restrict__ nbr_fea,
                            const int* __restrict__ nbr_idx,
                            const u16* __restrict__ wf,
                            float* __restrict__ stats,
                            float* __restrict__ out_ns) {
    __shared__ union {
        u16 a[BM * APAD];
        float act[BM * ACTPAD];
    } sh;

    const int t = threadIdx.x;
    const int w = t >> 6, l = t & 63, fr = l & 15, fq = l >> 4;
    const int ct0 = 2 * w;

    int colp[4];
    colp[0] = ct0 * 16 + fr;
    colp[1] = colp[0] + 16;
    colp[2] = colp[0] + 128;
    colp[3] = colp[1] + 128;

    float s1v[4], t1v[4];
    if (PASS == 2) {
        #pragma unroll
        for (int p = 0; p < 4; ++p) {
            s1v[p] = stats[S_S1 + colp[p]];
            t1v[p] = stats[S_T1 + colp[p]];
        }
    }
    float ls[4] = {0.f,0.f,0.f,0.f}, lq[4] = {0.f,0.f,0.f,0.f};
    float bsum = 0.f, bssq = 0.f;

    for (int tile = blockIdx.x; tile < NTILES; tile += GRID_P) {
        const int n0 = tile * 8;

        __syncthreads();
        for (int it = 0; it < 15; ++it) {
            int c = t + it * TPB;
            int row = c / 40;
            int seg = c - row * 40;
            int an = row / 12;
            int m  = row - an * 12;
            int na = n0 + an;
            const float* src;
            if (seg < 16) {
                src = atom_in + (size_t)na * A_FEA + seg * 8;
            } else if (seg < 32) {
                int j = nbr_idx[na * M_NBR + m];
                src = atom_in + (size_t)j * A_FEA + (seg - 16) * 8;
            } else {
                src = nbr_fea + ((size_t)na * M_NBR + m) * E_FEA + (seg - 32) * 8;
            }
            float4 x0 = *reinterpret_cast<const float4*>(src);
            float4 x1 = *reinterpret_cast<const float4*>(src + 4);
            uint4 pk;
            pk.x = (u32)f2bf(x0.x) | ((u32)f2bf(x0.y) << 16);
            pk.y = (u32)f2bf(x0.z) | ((u32)f2bf(x0.w) << 16);
            pk.z = (u32)f2bf(x1.x) | ((u32)f2bf(x1.y) << 16);
            pk.w = (u32)f2bf(x1.z) | ((u32)f2bf(x1.w) << 16);
            *reinterpret_cast<uint4*>(&sh.a[row * APAD + seg * 8]) = pk;
        }
        __syncthreads();

        f32x4 acc[6][4];
        #pragma unroll
        for (int rt = 0; rt < 6; ++rt)
            #pragma unroll
            for (int p = 0; p < 4; ++p)
                acc[rt][p] = (f32x4){0.f,0.f,0.f,0.f};

        for (int kt = 0; kt < 10; ++kt) {
            short8 af[6], bf[4];
            #pragma unroll
            for (int rt = 0; rt < 6; ++rt)
                af[rt] = *reinterpret_cast<const short8*>(
                    &sh.a[(rt * 16 + fr) * APAD + kt * 32 + fq * 8]);
            #pragma unroll
            for (int p = 0; p < 4; ++p) {
                int ct = (p < 2) ? (ct0 + p) : (ct0 + 8 + (p - 2));
                bf[p] = *reinterpret_cast<const short8*>(
                    &wf[((kt * 16 + ct) * 64 + l) * 8]);
            }
            #pragma unroll
            for (int rt = 0; rt < 6; ++rt)
                #pragma unroll
                for (int p = 0; p < 4; ++p)
                    acc[rt][p] = __builtin_amdgcn_mfma_f32_16x16x32_bf16(
                        af[rt], bf[p], acc[rt][p], 0, 0, 0);
        }

        if (PASS == 1) {
            #pragma unroll
            for (int p = 0; p < 4; ++p)
                #pragma unroll
                for (int rt = 0; rt < 6; ++rt)
                    #pragma unroll
                    for (int j = 0; j < 4; ++j) {
                        float v = acc[rt][p][j];
                        ls[p] += v;
                        lq[p] = fmaf(v, v, lq[p]);
                    }
        } else {
            __syncthreads();
            #pragma unroll
            for (int rt = 0; rt < 6; ++rt)
                #pragma unroll
                for (int p = 0; p < 2; ++p)
                    #pragma unroll
                    for (int j = 0; j < 4; ++j) {
                        float gf = fmaf(acc[rt][p][j],     s1v[p],     t1v[p]);
                        float gc = fmaf(acc[rt][2 + p][j], s1v[2 + p], t1v[2 + p]);
                        float a = sigmoid_f(gf) * softplus_f(gc);
                        int row = rt * 16 + fq * 4 + j;
                        int colact = ct0 * 16 + p * 16 + fr;
                        sh.act[row * ACTPAD + colact] = a;
                    }
            __syncthreads();
            #pragma unroll
            for (int i = 0; i < 4; ++i) {
                int o = i * TPB + t;
                int a = o >> 7;
                int c = o & 127;
                float S = 0.f;
                #pragma unroll
                for (int mm = 0; mm < 12; ++mm)
                    S += sh.act[(a * 12 + mm) * ACTPAD + c];
                out_ns[(size_t)(n0 + a) * A_FEA + c] = S;
                bsum += S;
                bssq = fmaf(S, S, bssq);
            }
        }
    }

    if (PASS == 1) {
        #pragma unroll
        for (int p = 0; p < 4; ++p) {
            float s = ls[p], q = lq[p];
            s += __shfl_xor(s, 16, 64);
            s += __shfl_xor(s, 32, 64);
            q += __shfl_xor(q, 16, 64);
            q += __shfl_xor(q, 32, 64);
            if (fq == 0) {
                atomicAdd(&stats[S_BN1SUM + colp[p]], s);
                atomicAdd(&stats[S_BN1SSQ + colp[p]], q);
            }
        }
    } else {
        __syncthreads();
        if (t >= 128) {
            sh.act[(t - 128) * 2]     = bsum;
            sh.act[(t - 128) * 2 + 1] = bssq;
        }
        __syncthreads();
        if (t < 128) {
            bsum += sh.act[t * 2];
            bssq += sh.act[t * 2 + 1];
            atomicAdd(&stats[S_BN2SUM + t], bsum);
            atomicAdd(&stats[S_BN2SSQ + t], bssq);
        }
    }
}

// =====================================================================
extern "C" void kernel_launch(void* const* d_in, const int* in_sizes, int n_in,
                              void* d_out, int out_size, void* d_ws, size_t ws_size,
                              hipStream_t stream) {
    (void)in_sizes; (void)n_in; (void)out_size;
    const float* atom_in = (const float*)d_in[0];
    const float* nbr_fea = (const float*)d_in[1];
    const int*   nbr_idx = (const int*)d_in[2];
    const float* Wfull   = (const float*)d_in[3];
    // d_in[4] = b_full: cancels exactly under batchnorm1 -> unused
    const float* g1      = (const float*)d_in[5];
    const float* b1      = (const float*)d_in[6];
    const float* g2      = (const float*)d_in[7];
    const float* b2      = (const float*)d_in[8];
    const float* Wsk     = (const float*)d_in[9];
    const float* bsk     = (const float*)d_in[10];
    float* out = (float*)d_out;

    float* stats = (float*)((char*)d_ws + STATS_OFF);
    u16* wskf = (u16*)((char*)d_ws + WSK_OFF);

    const size_t need_mid  = GATED_OFF;
    const size_t need_fast = GATED_OFF + GATED_BYTES;

    if (ws_size >= need_mid) {
        u16* wpq = (u16*)d_ws;
        u16* w3  = (u16*)((char*)d_ws + W3_OFF);
        u16* Pb  = (u16*)((char*)d_ws + P_OFF);
        u16* Qb  = (u16*)((char*)d_ws + Q_OFF);
        u16* gated = (u16*)((char*)d_ws + GATED_OFF);

        zero_stats<<<1, 256, 0, stream>>>(stats);
        prep_pack_fast<<<48, 256, 0, stream>>>(Wfull, Wsk, wpq, w3, wskf);
        pq_kernel<<<(N_ATOM + 63) / 64, 256, 0, stream>>>(atom_in, wpq, Pb, Qb);
        if (ws_size >= need_fast) {
            estage_kernel<1, 1><<<GRID_E, 512, 0, stream>>>(
                nbr_fea, nbr_idx, w3, Pb, Qb, stats, gated, out);
            finalize1<<<1, 256, 0, stream>>>(g1, b1, stats);
            apply_kernel<<<(N_ATOM + 63) / 64, 256, 0, stream>>>(gated, stats, out);
        } else {
            estage_kernel<1, 0><<<GRID_E, 512, 0, stream>>>(
                nbr_fea, nbr_idx, w3, Pb, Qb, stats, (u16*)d_ws, out);
            finalize1<<<1, 256, 0, stream>>>(g1, b1, stats);
            estage_kernel<2, 0><<<GRID_E, 512, 0, stream>>>(
                nbr_fea, nbr_idx, w3, Pb, Qb, stats, (u16*)d_ws, out);
        }
        finalize2<<<1, 128, 0, stream>>>(g2, b2, stats);
        skip_kernel<<<(N_ATOM + BM5 - 1) / BM5, 256, 0, stream>>>(atom_in, wskf, bsk, stats, out);
    } else {
        u16* wf = (u16*)d_ws;
        zero_stats<<<1, 256, 0, stream>>>(stats);
        prep_pack_slow<<<48, 256, 0, stream>>>(Wfull, Wsk, wf, wskf);
        pass_kernel<1><<<GRID_P, TPB, 0, stream>>>(atom_in, nbr_fea, nbr_idx, wf, stats, out);
        finalize1<<<1, 256, 0, stream>>>(g1, b1, stats);
        pass_kernel<2><<<GRID_P, TPB, 0, stream>>>(atom_in, nbr_fea, nbr_idx, wf, stats, out);
        finalize2<<<1, 128, 0, stream>>>(g2, b2, stats);
        skip_kernel<<<(N_ATOM + BM5 - 1) / BM5, 256, 0, stream>>>(atom_in, wskf, bsk, stats, out);
    }
}